// Round 5
// baseline (362.979 us; speedup 1.0000x reference)
//
#include <hip/hip_runtime.h>
#include <math.h>

#define N_NODES 50000
#define N_EDGES 800000
#define CAP 64                 // fixed CSR capacity/node (deg~Poisson(16))
#define RANGES 8
#define NODES_PER_RANGE 6250   // 50000 / 8
#define GEMMB 782              // ceil(50000/64)
#define CHUNKS (N_EDGES / 256) // 3125 edge chunks of 256
#define CPB 8                  // chunks per CSR block (latency batching)
#define BPR ((CHUNKS + CPB - 1) / CPB)   // 391 blocks per range
#define CSRB (BPR * RANGES)    // 3128 csr blocks
#define LROW 136               // LDS row stride in shorts (272 B)

typedef __attribute__((ext_vector_type(8))) short short8;   // 8 bf16
typedef __attribute__((ext_vector_type(4))) float f32x4;    // 4 fp32 acc

// ---------------- bf16 helpers (RNE) ----------------
__device__ __forceinline__ unsigned short f2bf(float f) {
    unsigned int u = __float_as_uint(f);
    return (unsigned short)((u + 0x7FFFu + ((u >> 16) & 1u)) >> 16);
}

// A fragment load: row-major fp32 (inline convert) or bf16.
template <bool F32>
__device__ __forceinline__ short8 loadA(const void* A, int off) {
    short8 r;
    if (F32) {
        const float* p = (const float*)A + off;   // 32B aligned
        float4 f0 = *(const float4*)p;
        float4 f1 = *(const float4*)(p + 4);
        r[0] = (short)f2bf(f0.x); r[1] = (short)f2bf(f0.y);
        r[2] = (short)f2bf(f0.z); r[3] = (short)f2bf(f0.w);
        r[4] = (short)f2bf(f1.x); r[5] = (short)f2bf(f1.y);
        r[6] = (short)f2bf(f1.z); r[7] = (short)f2bf(f1.w);
    } else {
        r = *(const short8*)((const unsigned short*)A + off);
    }
    return r;
}

// ---------------------------------------------------------------------------
// prep: pack 9 weight matrices fp32 -> bf16 fragment layout; zero deg.
// Bp[((c*N + n)*4 + q)*8 + j] = W[(c*32 + q*8 + j)*N + n].
// ---------------------------------------------------------------------------
struct WDescs { const float* W[9]; int N[9]; };

__global__ __launch_bounds__(256) void prep_kernel(
    WDescs wd, unsigned short* __restrict__ Wpk, int* __restrict__ deg)
{
    const int nthr = gridDim.x * 256;
    const int tid = blockIdx.x * 256 + threadIdx.x;
    for (int id = tid; id < 9 * 16384; id += nthr) {
        int mi = id >> 14;
        int loc = id & 16383;
        int N = wd.N[mi];
        if (loc < 128 * N) {
            int c = loc / (N * 32);
            int n = (loc - c * N * 32) >> 5;
            int k = c * 32 + (loc & 31);
            Wpk[mi * 16384 + loc] = f2bf(wd.W[mi][k * N + n]);
        }
    }
    for (int i = tid; i < N_NODES; i += nthr) deg[i] = 0;
}

// ---------------------------------------------------------------------------
// mix (R1 best-measured form, ~50us): blocks [0,GEMMB) compute
// Y1 = relu(x@Wp1+bp1); blocks [GEMMB,+CSRB) build CSR one-shot
// (XCD-range-partitioned, CPB=8 index-load batching).
// R1-R3 lesson: issue-side restructuring moved mix 50<->59us; the cost is
// the scattered-atomic/scatter-store machinery itself. Keep as-is.
// ---------------------------------------------------------------------------
__global__ __launch_bounds__(256) void mix_kernel(
    const int* __restrict__ esrc, const int* __restrict__ edst,
    int* __restrict__ deg, unsigned short* __restrict__ csr16,
    const float* __restrict__ x, const unsigned short* __restrict__ Wp1,
    const float* __restrict__ bp1, unsigned short* __restrict__ Y)
{
    if (blockIdx.x >= GEMMB) {
        const int b = blockIdx.x - GEMMB;
        const int range = b & (RANGES - 1);
        const int cbase = (b >> 3) * CPB;
        const int lo = range * NODES_PER_RANGE;
        int d[CPB], s[CPB];
        #pragma unroll
        for (int i = 0; i < CPB; ++i) {
            const int c = cbase + i;
            const int e = c * 256 + threadIdx.x;
            const bool ok = (c < CHUNKS);
            d[i] = ok ? edst[e] : -1;        // coalesced, 16 loads in flight
            s[i] = ok ? esrc[e] : 0;
        }
        #pragma unroll
        for (int i = 0; i < CPB; ++i) {
            if ((unsigned)(d[i] - lo) < (unsigned)NODES_PER_RANGE) {
                int r = atomicAdd(&deg[d[i]], 1);
                if (r < CAP) csr16[(d[i] << 6) + r] = (unsigned short)s[i];
            }
        }
        return;
    }
    const int lane = threadIdx.x & 63;
    const int wv = threadIdx.x >> 6;
    const int cl = lane & 15;
    const int quad = lane >> 4;
    const int rowBase = blockIdx.x * 64 + wv * 16;
    const int ar = min(rowBase + cl, N_NODES - 1);
    const int bLane = cl * 32 + quad * 8;

    f32x4 acc[8];
    #pragma unroll
    for (int t = 0; t < 8; ++t) acc[t] = (f32x4){0.f, 0.f, 0.f, 0.f};

    #pragma unroll
    for (int c = 0; c < 4; ++c) {
        short8 af = loadA<true>(x, ar * 128 + c * 32 + quad * 8);
        const unsigned short* Bc = Wp1 + c * 4096 + bLane;
        #pragma unroll
        for (int t = 0; t < 8; ++t) {
            short8 bf = *(const short8*)(Bc + t * 512);
            acc[t] = __builtin_amdgcn_mfma_f32_16x16x32_bf16(af, bf, acc[t], 0, 0, 0);
        }
    }
    const int row0 = rowBase + quad * 4;
    #pragma unroll
    for (int t = 0; t < 8; ++t) {
        float bc = bp1[t * 16 + cl];
        #pragma unroll
        for (int g = 0; g < 4; ++g) {
            int r = row0 + g;
            if (r < N_NODES)
                Y[r * 128 + t * 16 + cl] = f2bf(fmaxf(acc[t][g] + bc, 0.0f));
        }
    }
}

// ---------------------------------------------------------------------------
// fused: max-pool + dual-GEMM + l2norm + (next-layer y-GEMM | fp32 out).
// NEW vs r17 (R4 showed gather latency-bound: MfmaUtil 2.4%, occ 22%,
// only ~4 loads/lane in flight behind idx->row dependency + per-edge
// branches):
//  (a) all 32 CSR indices preloaded up front (4x uint4, always within the
//      64-entry row) -- no idx dependency left in the gather loop;
//  (b) branch-free gather: out-of-range edges clamp to edge 0 via cndmask
//      (re-maxing a valid neighbor row is a no-op for max-pool); the 128
//      row loads form ONE basic block so the scheduler keeps dozens in
//      flight, staged by vmcnt. Clamped loads re-hit edge-0's row in L1.
//  (c) __launch_bounds__(256,4) caps VGPR at 128 so the deep unroll can't
//      collapse occupancy.
// Zero-degree -> p stays 0 (uniform guard). deg>32 (P~1e-4) serial tail.
// relu'd bf16 >= 0 -> packed int16 max on raw bits exact; deterministic.
// ---------------------------------------------------------------------------
template <bool A0F32, bool LAST>
__global__ __launch_bounds__(256, 4) void fused_kernel(
    const void* __restrict__ A0,
    const unsigned short* __restrict__ Yl,          // gather source y_l
    const int* __restrict__ deg,
    const unsigned short* __restrict__ csr16,
    const unsigned short* __restrict__ B0, const unsigned short* __restrict__ B1,
    const float* __restrict__ bias,
    unsigned short* __restrict__ outH, float* __restrict__ outF,
    const unsigned short* __restrict__ Bnext, const float* __restrict__ bnext,
    unsigned short* __restrict__ Yout)
{
    constexpr int NT = LAST ? 4 : 8;
    constexpr int N = NT * 16;
    __shared__ unsigned short lds[4][16 * LROW];   // 17.4 KB, wave-private rows

    const int lane = threadIdx.x & 63;
    const int wv = threadIdx.x >> 6;
    const int cl = lane & 15;
    const int quad = lane >> 4;
    const int nodeBase = blockIdx.x * 64 + wv * 16;
    unsigned short* plw = &lds[wv][0];

    // ---- pool phase: 16 nodes/wave, 4 lanes/node, 32 dims/lane ----
    {
        const int n16 = lane >> 2;          // node within wave [0,16)
        const int g   = lane & 3;           // 64B dim slice [0,4)
        const int node = nodeBase + n16;
        const int nodeC = min(node, N_NODES - 1);
        const int myDeg = (node < N_NODES) ? min(deg[node], CAP) : 0;
        const unsigned short* csrn = csr16 + (nodeC << 6);
        const unsigned short* yg = Yl + g * 32;

        // preload 32 indices (P(deg>32) ~ 1e-4); row always has 64 entries
        unsigned int idxw[16];
        *(uint4*)(idxw +  0) = *(const uint4*)(csrn +  0);
        *(uint4*)(idxw +  4) = *(const uint4*)(csrn +  8);
        *(uint4*)(idxw +  8) = *(const uint4*)(csrn + 16);
        *(uint4*)(idxw + 12) = *(const uint4*)(csrn + 24);

        short8 p0 = (short8){0,0,0,0,0,0,0,0};
        short8 p1 = p0, p2 = p0, p3 = p0;

        if (myDeg > 0) {
            const int s0 = (int)(idxw[0] & 0xFFFFu);   // edge 0 (always valid)
            #pragma unroll
            for (int j = 0; j < 32; ++j) {             // constant j -> reg indices
                int sj = (j & 1) ? (int)(idxw[j >> 1] >> 16)
                                 : (int)(idxw[j >> 1] & 0xFFFFu);
                sj = (j < myDeg) ? sj : s0;            // cndmask, no branch
                const short8* r = (const short8*)(yg + (sj << 7));
                p0 = __builtin_elementwise_max(p0, r[0]);
                p1 = __builtin_elementwise_max(p1, r[1]);
                p2 = __builtin_elementwise_max(p2, r[2]);
                p3 = __builtin_elementwise_max(p3, r[3]);
            }
            for (int k = 32; k < myDeg; ++k) {         // rare tail
                const int sv = csrn[k];
                const short8* r = (const short8*)(yg + (sv << 7));
                p0 = __builtin_elementwise_max(p0, r[0]);
                p1 = __builtin_elementwise_max(p1, r[1]);
                p2 = __builtin_elementwise_max(p2, r[2]);
                p3 = __builtin_elementwise_max(p3, r[3]);
            }
        }
        unsigned short* pw = plw + n16 * LROW + g * 32;
        *(short8*)(pw)      = p0;
        *(short8*)(pw + 8)  = p1;
        *(short8*)(pw + 16) = p2;
        *(short8*)(pw + 24) = p3;
        // no barrier: this wave wrote rows it alone will read (DS in-order)
    }

    const int ar = min(nodeBase + cl, N_NODES - 1);
    const int aBase = ar * 128 + quad * 8;
    const int fBase = cl * LROW + quad * 8;     // LDS A-fragment base
    const int bLane = cl * 32 + quad * 8;

    f32x4 acc[NT];
    #pragma unroll
    for (int t = 0; t < NT; ++t) acc[t] = (f32x4){0.f, 0.f, 0.f, 0.f};

    #pragma unroll
    for (int c = 0; c < 4; ++c) {
        short8 a0 = loadA<A0F32>(A0, aBase + c * 32);
        short8 a1 = *(const short8*)(plw + fBase + c * 32);
        const unsigned short* B0c = B0 + c * (N * 32) + bLane;
        const unsigned short* B1c = B1 + c * (N * 32) + bLane;
        #pragma unroll
        for (int t = 0; t < NT; ++t) {
            short8 bf = *(const short8*)(B0c + t * 512);
            acc[t] = __builtin_amdgcn_mfma_f32_16x16x32_bf16(a0, bf, acc[t], 0, 0, 0);
        }
        #pragma unroll
        for (int t = 0; t < NT; ++t) {
            short8 bf = *(const short8*)(B1c + t * 512);
            acc[t] = __builtin_amdgcn_mfma_f32_16x16x32_bf16(a1, bf, acc[t], 0, 0, 0);
        }
    }

    #pragma unroll
    for (int t = 0; t < NT; ++t) {
        float bc = bias[t * 16 + cl];
        #pragma unroll
        for (int g = 0; g < 4; ++g) acc[t][g] += bc;
    }

    // ---- fused row-wise L2 norm (row lives in 16 lanes of this quad group) ----
    float inv[4];
    #pragma unroll
    for (int g = 0; g < 4; ++g) {
        float s = 0.f;
        #pragma unroll
        for (int t = 0; t < NT; ++t) s += acc[t][g] * acc[t][g];
        s += __shfl_xor(s, 1, 64);
        s += __shfl_xor(s, 2, 64);
        s += __shfl_xor(s, 4, 64);
        s += __shfl_xor(s, 8, 64);
        inv[g] = 1.0f / fmaxf(sqrtf(s), 1e-12f);
    }

    const int row0 = nodeBase + quad * 4;

    if (LAST) {
        #pragma unroll
        for (int t = 0; t < NT; ++t)
            #pragma unroll
            for (int g = 0; g < 4; ++g) {
                int r = row0 + g;
                if (r < N_NODES)
                    outF[r * N + t * 16 + cl] = fmaxf(acc[t][g] * inv[g], 0.0f);
            }
        return;
    }

    // h -> global (next fused's A0) + LDS stage (C-layout -> A-layout).
    // Overwrites the pool staging rows -- safe: all a1 reads precede these
    // writes in program order (same wave, DS in-order).
    #pragma unroll
    for (int t = 0; t < NT; ++t)
        #pragma unroll
        for (int g = 0; g < 4; ++g) {
            int r = row0 + g;
            unsigned short h = f2bf(fmaxf(acc[t][g] * inv[g], 0.0f));
            if (r < N_NODES) outH[r * 128 + t * 16 + cl] = h;
            plw[(quad * 4 + g) * LROW + t * 16 + cl] = h;
        }

    // ---- y-GEMM for the next layer: Yout = relu(h @ Bnext + bnext) ----
    f32x4 ya[8];
    #pragma unroll
    for (int t = 0; t < 8; ++t) ya[t] = (f32x4){0.f, 0.f, 0.f, 0.f};
    #pragma unroll
    for (int c = 0; c < 4; ++c) {
        short8 af = *(const short8*)(plw + cl * LROW + c * 32 + quad * 8);
        const unsigned short* Bc = Bnext + c * 4096 + bLane;
        #pragma unroll
        for (int t = 0; t < 8; ++t) {
            short8 bf = *(const short8*)(Bc + t * 512);
            ya[t] = __builtin_amdgcn_mfma_f32_16x16x32_bf16(af, bf, ya[t], 0, 0, 0);
        }
    }
    #pragma unroll
    for (int t = 0; t < 8; ++t) {
        float bc = bnext[t * 16 + cl];
        #pragma unroll
        for (int g = 0; g < 4; ++g) {
            int r = row0 + g;
            if (r < N_NODES)
                Yout[r * 128 + t * 16 + cl] = f2bf(fmaxf(ya[t][g] + bc, 0.0f));
        }
    }
}

extern "C" void kernel_launch(void* const* d_in, const int* in_sizes, int n_in,
                              void* d_out, int out_size, void* d_ws, size_t ws_size,
                              hipStream_t stream) {
    const float* x    = (const float*)d_in[0];
    const int*   esrc = (const int*)d_in[1];
    const int*   edst = (const int*)d_in[2];
    const float* Wp[3], *bp[3], *Ws[3], *Wn[3], *bb[3];
    for (int l = 0; l < 3; ++l) {
        Wp[l] = (const float*)d_in[3 + 5 * l];
        bp[l] = (const float*)d_in[4 + 5 * l];
        Ws[l] = (const float*)d_in[5 + 5 * l];
        Wn[l] = (const float*)d_in[6 + 5 * l];
        bb[l] = (const float*)d_in[7 + 5 * l];
    }

    const int NF = N_NODES * 128;
    unsigned short* YA  = (unsigned short*)d_ws;     // y ping
    unsigned short* YB  = YA + NF;                   // y pong
    unsigned short* PL  = YB + NF;                   // (unused; kept for layout)
    unsigned short* H1  = PL + NF;                   // h1
    unsigned short* H2  = H1 + NF;                   // h2
    unsigned short* Wpk = H2 + NF;                   // 9 * 16384 packed weights
    int* deg = (int*)(Wpk + 9 * 16384);              // 50000
    unsigned short* csr16 = (unsigned short*)(deg + N_NODES); // 50000*64

    auto WH = [&](int i) { return Wpk + i * 16384; };
    // order: 0=Wp1 1=Ws1 2=Wn1 3=Wp2 4=Ws2 5=Wn2 6=Wp3 7=Ws3 8=Wn3

    WDescs wd;
    wd.W[0] = Wp[0]; wd.N[0] = 128;
    wd.W[1] = Ws[0]; wd.N[1] = 128;
    wd.W[2] = Wn[0]; wd.N[2] = 128;
    wd.W[3] = Wp[1]; wd.N[3] = 128;
    wd.W[4] = Ws[1]; wd.N[4] = 128;
    wd.W[5] = Wn[1]; wd.N[5] = 128;
    wd.W[6] = Wp[2]; wd.N[6] = 128;
    wd.W[7] = Ws[2]; wd.N[7] = 64;
    wd.W[8] = Wn[2]; wd.N[8] = 64;

    // 1) prep: pack weights + zero deg
    prep_kernel<<<576, 256, 0, stream>>>(wd, Wpk, deg);
    // 2) Y1 = relu(x@Wp1+bp1) + one-shot CSR fill (R1 best-measured form)
    mix_kernel<<<GEMMB + CSRB, 256, 0, stream>>>(esrc, edst, deg, csr16,
                                                 x, WH(0), bp[0], YA);
    // 3) layer 1 (pool fused): gathers YA, A0 = x (fp32)
    fused_kernel<true, false><<<GEMMB, 256, 0, stream>>>(
        x, YA, deg, csr16, WH(1), WH(2), bb[0], H1, nullptr, WH(3), bp[1], YB);
    // 4) layer 2: gathers YB, A0 = H1
    fused_kernel<false, false><<<GEMMB, 256, 0, stream>>>(
        H1, YB, deg, csr16, WH(4), WH(5), bb[1], H2, nullptr, WH(6), bp[2], YA);
    // 5) layer 3: gathers YA, A0 = H2, fp32 out
    fused_kernel<false, true><<<GEMMB, 256, 0, stream>>>(
        H2, YA, deg, csr16, WH(7), WH(8), bb[2], nullptr, (float*)d_out,
        nullptr, nullptr, nullptr);
}

// Round 7
// 351.943 us; speedup vs baseline: 1.0314x; 1.0314x over previous
//
#include <hip/hip_runtime.h>
#include <math.h>

#define N_NODES 50000
#define N_EDGES 800000
#define CAP 64                 // fixed CSR capacity/node (deg~Poisson(16))
#define RANGES 8
#define NODES_PER_RANGE 6250   // 50000 / 8
#define GEMMB 782              // ceil(50000/64)
#define CHUNKS (N_EDGES / 256) // 3125 edge chunks of 256
#define CPB 8                  // chunks per CSR block (latency batching)
#define BPR ((CHUNKS + CPB - 1) / CPB)   // 391 blocks per range
#define CSRB (BPR * RANGES)    // 3128 csr blocks
#define LROW 136               // LDS row stride in shorts (272 B)
#define PLANE_SHORTS (N_NODES * 32)     // one 32-dim plane of Y (3.2 MB)
#define POOLB 3128             // 8 (xcd) * 391 node-chunks

typedef __attribute__((ext_vector_type(8))) short short8;   // 8 bf16
typedef __attribute__((ext_vector_type(4))) float f32x4;    // 4 fp32 acc
typedef __attribute__((ext_vector_type(4))) unsigned int uint4v; // clang vec

// ---------------- bf16 helpers (RNE) ----------------
__device__ __forceinline__ unsigned short f2bf(float f) {
    unsigned int u = __float_as_uint(f);
    return (unsigned short)((u + 0x7FFFu + ((u >> 16) & 1u)) >> 16);
}

// A fragment load: row-major fp32 (inline convert) or bf16.
template <bool F32>
__device__ __forceinline__ short8 loadA(const void* A, int off) {
    short8 r;
    if (F32) {
        const float* p = (const float*)A + off;   // 32B aligned
        float4 f0 = *(const float4*)p;
        float4 f1 = *(const float4*)(p + 4);
        r[0] = (short)f2bf(f0.x); r[1] = (short)f2bf(f0.y);
        r[2] = (short)f2bf(f0.z); r[3] = (short)f2bf(f0.w);
        r[4] = (short)f2bf(f1.x); r[5] = (short)f2bf(f1.y);
        r[6] = (short)f2bf(f1.z); r[7] = (short)f2bf(f1.w);
    } else {
        r = *(const short8*)((const unsigned short*)A + off);
    }
    return r;
}

// plane-layout Y store helper: dim = t*16+cl in [0,128) -> plane dim>>5,
// in-plane offset r*32 + (dim&31). Still lane-coalesced (cl consecutive).
__device__ __forceinline__ void storeYplane(unsigned short* Y, int r, int t,
                                            int cl, unsigned short v) {
    const int dim = t * 16 + cl;
    Y[(dim >> 5) * PLANE_SHORTS + r * 32 + (dim & 31)] = v;
}

// ---------------------------------------------------------------------------
// prep: pack 9 weight matrices fp32 -> bf16 fragment layout; zero deg.
// Bp[((c*N + n)*4 + q)*8 + j] = W[(c*32 + q*8 + j)*N + n].
// ---------------------------------------------------------------------------
struct WDescs { const float* W[9]; int N[9]; };

__global__ __launch_bounds__(256) void prep_kernel(
    WDescs wd, unsigned short* __restrict__ Wpk, int* __restrict__ deg)
{
    const int nthr = gridDim.x * 256;
    const int tid = blockIdx.x * 256 + threadIdx.x;
    for (int id = tid; id < 9 * 16384; id += nthr) {
        int mi = id >> 14;
        int loc = id & 16383;
        int N = wd.N[mi];
        if (loc < 128 * N) {
            int c = loc / (N * 32);
            int n = (loc - c * N * 32) >> 5;
            int k = c * 32 + (loc & 31);
            Wpk[mi * 16384 + loc] = f2bf(wd.W[mi][k * N + n]);
        }
    }
    for (int i = tid; i < N_NODES; i += nthr) deg[i] = 0;
}

// ---------------------------------------------------------------------------
// mix (R1 best-measured form, ~50us): blocks [0,GEMMB) compute
// Y1 = relu(x@Wp1+bp1) (PLANE layout); blocks [GEMMB,+CSRB) build CSR
// one-shot (XCD-range-partitioned, CPB=8 index-load batching).
// R1-R3 lesson: issue-side restructuring moved mix 50<->59us; keep as-is.
// ---------------------------------------------------------------------------
__global__ __launch_bounds__(256) void mix_kernel(
    const int* __restrict__ esrc, const int* __restrict__ edst,
    int* __restrict__ deg, unsigned short* __restrict__ csr16,
    const float* __restrict__ x, const unsigned short* __restrict__ Wp1,
    const float* __restrict__ bp1, unsigned short* __restrict__ Y)
{
    if (blockIdx.x >= GEMMB) {
        const int b = blockIdx.x - GEMMB;
        const int range = b & (RANGES - 1);
        const int cbase = (b >> 3) * CPB;
        const int lo = range * NODES_PER_RANGE;
        int d[CPB], s[CPB];
        #pragma unroll
        for (int i = 0; i < CPB; ++i) {
            const int c = cbase + i;
            const int e = c * 256 + threadIdx.x;
            const bool ok = (c < CHUNKS);
            d[i] = ok ? edst[e] : -1;        // coalesced, 16 loads in flight
            s[i] = ok ? esrc[e] : 0;
        }
        #pragma unroll
        for (int i = 0; i < CPB; ++i) {
            if ((unsigned)(d[i] - lo) < (unsigned)NODES_PER_RANGE) {
                int r = atomicAdd(&deg[d[i]], 1);
                if (r < CAP) csr16[(d[i] << 6) + r] = (unsigned short)s[i];
            }
        }
        return;
    }
    const int lane = threadIdx.x & 63;
    const int wv = threadIdx.x >> 6;
    const int cl = lane & 15;
    const int quad = lane >> 4;
    const int rowBase = blockIdx.x * 64 + wv * 16;
    const int ar = min(rowBase + cl, N_NODES - 1);
    const int bLane = cl * 32 + quad * 8;

    f32x4 acc[8];
    #pragma unroll
    for (int t = 0; t < 8; ++t) acc[t] = (f32x4){0.f, 0.f, 0.f, 0.f};

    #pragma unroll
    for (int c = 0; c < 4; ++c) {
        short8 af = loadA<true>(x, ar * 128 + c * 32 + quad * 8);
        const unsigned short* Bc = Wp1 + c * 4096 + bLane;
        #pragma unroll
        for (int t = 0; t < 8; ++t) {
            short8 bf = *(const short8*)(Bc + t * 512);
            acc[t] = __builtin_amdgcn_mfma_f32_16x16x32_bf16(af, bf, acc[t], 0, 0, 0);
        }
    }
    const int row0 = rowBase + quad * 4;
    #pragma unroll
    for (int t = 0; t < 8; ++t) {
        float bc = bp1[t * 16 + cl];
        #pragma unroll
        for (int g = 0; g < 4; ++g) {
            int r = row0 + g;
            if (r < N_NODES)
                storeYplane(Y, r, t, cl, f2bf(fmaxf(acc[t][g] + bc, 0.0f)));
        }
    }
}

// ---------------------------------------------------------------------------
// pool_plane: dim-plane-partitioned max-pool.
// THEORY (R4/R5): fused gather FETCH ~100MB == 12.8MB(Y) x 8 XCDs --
// compulsory L2 fills of the whole Y per XCD, random 128B lines from L3 at
// ~1.6 TB/s = the wall. Fix: Y stored as 4 planes of 32 dims (3.2MB each,
// fits 4MB L2; 128B lines never shared across planes). plane = blockIdx&3,
// blockIdx&7 -> XCD (round-robin dispatch heuristic): each XCD touches ONE
// plane -> per-XCD fill 3.2MB, chip total ~26MB (4x less), 16x in-L2 reuse.
// Geometry: 64 nodes/block, 4 lanes/node (16B each), 3128 blocks (12/CU).
// Gather: idx preloaded (nontemporal), batches of 8 loads clamp-style (re-
// maxing a valid row is a no-op), no VGPR cap. PL written row-major
// (nontemporal, consumed by dualy next dispatch).
// ---------------------------------------------------------------------------
__global__ __launch_bounds__(256) void pool_plane(
    const unsigned short* __restrict__ Yp,   // 4 planes
    const int* __restrict__ deg,
    const unsigned short* __restrict__ csr16,
    unsigned short* __restrict__ pool)       // row-major [N][128]
{
    const int q = blockIdx.x & 7;        // intended XCD
    const int plane = q & 3;
    const int halfN = q >> 2;
    const int chunk = blockIdx.x >> 3;   // 0..390 within (plane,half)
    const int n64 = threadIdx.x >> 2;    // node within block [0,64)
    const int j = threadIdx.x & 3;       // 16B quarter of the 64B slice
    const int local = chunk * 64 + n64;
    const int node = halfN * 25000 + local;
    if (local >= 25000 || node >= N_NODES) return;

    const int myDeg = min(deg[node], CAP);
    const unsigned short* csrn = csr16 + (node << 6);
    const unsigned short* yg = Yp + plane * PLANE_SHORTS + j * 8;

    short8 p0 = (short8){0, 0, 0, 0, 0, 0, 0, 0};
    if (myDeg > 0) {
        unsigned int idxw[16];
        *(uint4v*)(idxw + 0)  = __builtin_nontemporal_load((const uint4v*)(csrn));
        *(uint4v*)(idxw + 4)  = __builtin_nontemporal_load((const uint4v*)(csrn + 8));
        *(uint4v*)(idxw + 8)  = __builtin_nontemporal_load((const uint4v*)(csrn + 16));
        *(uint4v*)(idxw + 12) = __builtin_nontemporal_load((const uint4v*)(csrn + 24));
        const int s0 = (int)(idxw[0] & 0xFFFFu);       // edge 0 always valid
        #pragma unroll
        for (int b = 0; b < 4; ++b) {                  // batches of 8 edges
            if (b * 8 < myDeg) {
                short8 v[8];
                #pragma unroll
                for (int u = 0; u < 8; ++u) {
                    const int jj = b * 8 + u;
                    int sj = (jj & 1) ? (int)(idxw[jj >> 1] >> 16)
                                      : (int)(idxw[jj >> 1] & 0xFFFFu);
                    sj = (jj < myDeg) ? sj : s0;       // cndmask clamp
                    v[u] = *(const short8*)(yg + sj * 32);
                }
                #pragma unroll
                for (int u = 0; u < 8; ++u)
                    p0 = __builtin_elementwise_max(p0, v[u]);
            }
        }
        for (int k = 32; k < myDeg; ++k) {             // rare tail (P~1e-4)
            const int sv = csrn[k];
            p0 = __builtin_elementwise_max(p0, *(const short8*)(yg + sv * 32));
        }
    }
    __builtin_nontemporal_store(p0,
        (short8*)(pool + node * 128 + plane * 32 + j * 8));
}

// ---------------------------------------------------------------------------
// dualy (R0-R3 known-good form): dual-GEMM + l2norm + (next-layer y-GEMM |
// fp32 out). h staged through this wave's private LDS region (C-layout ->
// A-layout round trip, no __syncthreads: same-wave DS ops are in-order).
// Only change: Yout written in PLANE layout for pool_plane.
// ---------------------------------------------------------------------------
template <bool A0F32, bool LAST>
__global__ __launch_bounds__(256) void dualy_kernel(
    const void* __restrict__ A0,
    const unsigned short* __restrict__ B0, const unsigned short* __restrict__ B1,
    const float* __restrict__ bias,
    const unsigned short* __restrict__ PL,
    unsigned short* __restrict__ outH, float* __restrict__ outF,
    const unsigned short* __restrict__ Bnext, const float* __restrict__ bnext,
    unsigned short* __restrict__ Yout)
{
    constexpr int NT = LAST ? 4 : 8;
    constexpr int N = NT * 16;
    __shared__ unsigned short lds[4][16 * LROW];   // 17.4 KB (h staging)

    const int lane = threadIdx.x & 63;
    const int wv = threadIdx.x >> 6;
    const int cl = lane & 15;
    const int quad = lane >> 4;
    const int nodeBase = blockIdx.x * 64 + wv * 16;
    unsigned short* plw = &lds[wv][0];

    const int ar = min(nodeBase + cl, N_NODES - 1);
    const int aBase = ar * 128 + quad * 8;
    const int bLane = cl * 32 + quad * 8;

    f32x4 acc[NT];
    #pragma unroll
    for (int t = 0; t < NT; ++t) acc[t] = (f32x4){0.f, 0.f, 0.f, 0.f};

    #pragma unroll
    for (int c = 0; c < 4; ++c) {
        short8 a0 = loadA<A0F32>(A0, aBase + c * 32);
        short8 a1 = *(const short8*)(PL + aBase + c * 32);
        const unsigned short* B0c = B0 + c * (N * 32) + bLane;
        const unsigned short* B1c = B1 + c * (N * 32) + bLane;
        #pragma unroll
        for (int t = 0; t < NT; ++t) {
            short8 bf = *(const short8*)(B0c + t * 512);
            acc[t] = __builtin_amdgcn_mfma_f32_16x16x32_bf16(a0, bf, acc[t], 0, 0, 0);
        }
        #pragma unroll
        for (int t = 0; t < NT; ++t) {
            short8 bf = *(const short8*)(B1c + t * 512);
            acc[t] = __builtin_amdgcn_mfma_f32_16x16x32_bf16(a1, bf, acc[t], 0, 0, 0);
        }
    }

    #pragma unroll
    for (int t = 0; t < NT; ++t) {
        float bc = bias[t * 16 + cl];
        #pragma unroll
        for (int g = 0; g < 4; ++g) acc[t][g] += bc;
    }

    // ---- fused row-wise L2 norm (row lives in 16 lanes of this quad group) ----
    float inv[4];
    #pragma unroll
    for (int g = 0; g < 4; ++g) {
        float s = 0.f;
        #pragma unroll
        for (int t = 0; t < NT; ++t) s += acc[t][g] * acc[t][g];
        s += __shfl_xor(s, 1, 64);
        s += __shfl_xor(s, 2, 64);
        s += __shfl_xor(s, 4, 64);
        s += __shfl_xor(s, 8, 64);
        inv[g] = 1.0f / fmaxf(sqrtf(s), 1e-12f);
    }

    const int row0 = nodeBase + quad * 4;

    if (LAST) {
        #pragma unroll
        for (int t = 0; t < NT; ++t)
            #pragma unroll
            for (int g = 0; g < 4; ++g) {
                int r = row0 + g;
                if (r < N_NODES)
                    outF[r * N + t * 16 + cl] = fmaxf(acc[t][g] * inv[g], 0.0f);
            }
        return;
    }

    // h -> global (next dualy's A0) + LDS stage (C-layout -> A-layout)
    #pragma unroll
    for (int t = 0; t < NT; ++t)
        #pragma unroll
        for (int g = 0; g < 4; ++g) {
            int r = row0 + g;
            unsigned short h = f2bf(fmaxf(acc[t][g] * inv[g], 0.0f));
            if (r < N_NODES) outH[r * 128 + t * 16 + cl] = h;
            plw[(quad * 4 + g) * LROW + t * 16 + cl] = h;
        }

    // ---- y-GEMM for the next layer: Yout = relu(h @ Bnext + bnext) ----
    f32x4 ya[8];
    #pragma unroll
    for (int t = 0; t < 8; ++t) ya[t] = (f32x4){0.f, 0.f, 0.f, 0.f};
    #pragma unroll
    for (int c = 0; c < 4; ++c) {
        short8 af = *(const short8*)(plw + cl * LROW + c * 32 + quad * 8);
        const unsigned short* Bc = Bnext + c * 4096 + bLane;
        #pragma unroll
        for (int t = 0; t < 8; ++t) {
            short8 bf = *(const short8*)(Bc + t * 512);
            ya[t] = __builtin_amdgcn_mfma_f32_16x16x32_bf16(af, bf, ya[t], 0, 0, 0);
        }
    }
    #pragma unroll
    for (int t = 0; t < 8; ++t) {
        float bc = bnext[t * 16 + cl];
        #pragma unroll
        for (int g = 0; g < 4; ++g) {
            int r = row0 + g;
            if (r < N_NODES)
                storeYplane(Yout, r, t, cl, f2bf(fmaxf(ya[t][g] + bc, 0.0f)));
        }
    }
}

extern "C" void kernel_launch(void* const* d_in, const int* in_sizes, int n_in,
                              void* d_out, int out_size, void* d_ws, size_t ws_size,
                              hipStream_t stream) {
    const float* x    = (const float*)d_in[0];
    const int*   esrc = (const int*)d_in[1];
    const int*   edst = (const int*)d_in[2];
    const float* Wp[3], *bp[3], *Ws[3], *Wn[3], *bb[3];
    for (int l = 0; l < 3; ++l) {
        Wp[l] = (const float*)d_in[3 + 5 * l];
        bp[l] = (const float*)d_in[4 + 5 * l];
        Ws[l] = (const float*)d_in[5 + 5 * l];
        Wn[l] = (const float*)d_in[6 + 5 * l];
        bb[l] = (const float*)d_in[7 + 5 * l];
    }

    const int NF = N_NODES * 128;
    unsigned short* YA  = (unsigned short*)d_ws;     // y ping (4-plane layout)
    unsigned short* YB  = YA + NF;                   // y pong (4-plane layout)
    unsigned short* PL  = YB + NF;                   // pool (row-major)
    unsigned short* H1  = PL + NF;                   // h1
    unsigned short* H2  = H1 + NF;                   // h2
    unsigned short* Wpk = H2 + NF;                   // 9 * 16384 packed weights
    int* deg = (int*)(Wpk + 9 * 16384);              // 50000
    unsigned short* csr16 = (unsigned short*)(deg + N_NODES); // 50000*64

    auto WH = [&](int i) { return Wpk + i * 16384; };
    // order: 0=Wp1 1=Ws1 2=Wn1 3=Wp2 4=Ws2 5=Wn2 6=Wp3 7=Ws3 8=Wn3

    WDescs wd;
    wd.W[0] = Wp[0]; wd.N[0] = 128;
    wd.W[1] = Ws[0]; wd.N[1] = 128;
    wd.W[2] = Wn[0]; wd.N[2] = 128;
    wd.W[3] = Wp[1]; wd.N[3] = 128;
    wd.W[4] = Ws[1]; wd.N[4] = 128;
    wd.W[5] = Wn[1]; wd.N[5] = 128;
    wd.W[6] = Wp[2]; wd.N[6] = 128;
    wd.W[7] = Ws[2]; wd.N[7] = 64;
    wd.W[8] = Wn[2]; wd.N[8] = 64;

    // 1) prep: pack weights + zero deg
    prep_kernel<<<576, 256, 0, stream>>>(wd, Wpk, deg);
    // 2) Y1 = relu(x@Wp1+bp1) (plane layout) + one-shot CSR fill
    mix_kernel<<<GEMMB + CSRB, 256, 0, stream>>>(esrc, edst, deg, csr16,
                                                 x, WH(0), bp[0], YA);
    // 3) layer 1: XCD-local plane pool, then dual-GEMM
    pool_plane<<<POOLB, 256, 0, stream>>>(YA, deg, csr16, PL);
    dualy_kernel<true, false><<<GEMMB, 256, 0, stream>>>(
        x, WH(1), WH(2), bb[0], PL, H1, nullptr, WH(3), bp[1], YB);
    // 4) layer 2
    pool_plane<<<POOLB, 256, 0, stream>>>(YB, deg, csr16, PL);
    dualy_kernel<false, false><<<GEMMB, 256, 0, stream>>>(
        H1, WH(4), WH(5), bb[1], PL, H2, nullptr, WH(6), bp[2], YA);
    // 5) layer 3
    pool_plane<<<POOLB, 256, 0, stream>>>(YA, deg, csr16, PL);
    dualy_kernel<false, true><<<GEMMB, 256, 0, stream>>>(
        H2, WH(7), WH(8), bb[2], PL, nullptr, (float*)d_out,
        nullptr, nullptr, nullptr);
}

// Round 8
// 338.008 us; speedup vs baseline: 1.0739x; 1.0412x over previous
//
#include <hip/hip_runtime.h>
#include <math.h>

#define N_NODES 50000
#define N_EDGES 800000
#define CAP 64                 // fixed CSR capacity/node (deg~Poisson(16))
#define RANGES 8
#define NODES_PER_RANGE 6250   // 50000 / 8
#define GEMMB 782              // ceil(50000/64)
#define CHUNKS (N_EDGES / 256) // 3125 edge chunks of 256
#define CPB 8                  // chunks per CSR block (latency batching)
#define BPR ((CHUNKS + CPB - 1) / CPB)   // 391 blocks per range
#define CSRB (BPR * RANGES)    // 3128 csr blocks
#define LROW 136               // LDS row stride in shorts (272 B)

typedef __attribute__((ext_vector_type(8))) short short8;   // 8 bf16
typedef __attribute__((ext_vector_type(4))) float f32x4;    // 4 fp32 acc

// ---------------- bf16 helpers (RNE) ----------------
__device__ __forceinline__ unsigned short f2bf(float f) {
    unsigned int u = __float_as_uint(f);
    return (unsigned short)((u + 0x7FFFu + ((u >> 16) & 1u)) >> 16);
}

// A fragment load: row-major fp32 (inline convert) or bf16.
template <bool F32>
__device__ __forceinline__ short8 loadA(const void* A, int off) {
    short8 r;
    if (F32) {
        const float* p = (const float*)A + off;   // 32B aligned
        float4 f0 = *(const float4*)p;
        float4 f1 = *(const float4*)(p + 4);
        r[0] = (short)f2bf(f0.x); r[1] = (short)f2bf(f0.y);
        r[2] = (short)f2bf(f0.z); r[3] = (short)f2bf(f0.w);
        r[4] = (short)f2bf(f1.x); r[5] = (short)f2bf(f1.y);
        r[6] = (short)f2bf(f1.z); r[7] = (short)f2bf(f1.w);
    } else {
        r = *(const short8*)((const unsigned short*)A + off);
    }
    return r;
}

// ---------------------------------------------------------------------------
// prep: pack 9 weight matrices fp32 -> bf16 fragment layout; zero deg.
// Bp[((c*N + n)*4 + q)*8 + j] = W[(c*32 + q*8 + j)*N + n].
// ---------------------------------------------------------------------------
struct WDescs { const float* W[9]; int N[9]; };

__global__ __launch_bounds__(256) void prep_kernel(
    WDescs wd, unsigned short* __restrict__ Wpk, int* __restrict__ deg)
{
    const int nthr = gridDim.x * 256;
    const int tid = blockIdx.x * 256 + threadIdx.x;
    for (int id = tid; id < 9 * 16384; id += nthr) {
        int mi = id >> 14;
        int loc = id & 16383;
        int N = wd.N[mi];
        if (loc < 128 * N) {
            int c = loc / (N * 32);
            int n = (loc - c * N * 32) >> 5;
            int k = c * 32 + (loc & 31);
            Wpk[mi * 16384 + loc] = f2bf(wd.W[mi][k * N + n]);
        }
    }
    for (int i = tid; i < N_NODES; i += nthr) deg[i] = 0;
}

// ---------------------------------------------------------------------------
// mix (R1 best-measured form, ~50us): blocks [0,GEMMB) compute
// Y1 = relu(x@Wp1+bp1); blocks [GEMMB,+CSRB) build CSR one-shot
// (XCD-range-partitioned, CPB=8 index-load batching).
// R1-R3 lesson: issue-side restructuring moved mix 50<->59us; the cost is
// the scattered-atomic/scatter-store machinery itself. Keep as-is.
// ---------------------------------------------------------------------------
__global__ __launch_bounds__(256) void mix_kernel(
    const int* __restrict__ esrc, const int* __restrict__ edst,
    int* __restrict__ deg, unsigned short* __restrict__ csr16,
    const float* __restrict__ x, const unsigned short* __restrict__ Wp1,
    const float* __restrict__ bp1, unsigned short* __restrict__ Y)
{
    if (blockIdx.x >= GEMMB) {
        const int b = blockIdx.x - GEMMB;
        const int range = b & (RANGES - 1);
        const int cbase = (b >> 3) * CPB;
        const int lo = range * NODES_PER_RANGE;
        int d[CPB], s[CPB];
        #pragma unroll
        for (int i = 0; i < CPB; ++i) {
            const int c = cbase + i;
            const int e = c * 256 + threadIdx.x;
            const bool ok = (c < CHUNKS);
            d[i] = ok ? edst[e] : -1;        // coalesced, 16 loads in flight
            s[i] = ok ? esrc[e] : 0;
        }
        #pragma unroll
        for (int i = 0; i < CPB; ++i) {
            if ((unsigned)(d[i] - lo) < (unsigned)NODES_PER_RANGE) {
                int r = atomicAdd(&deg[d[i]], 1);
                if (r < CAP) csr16[(d[i] << 6) + r] = (unsigned short)s[i];
            }
        }
        return;
    }
    const int lane = threadIdx.x & 63;
    const int wv = threadIdx.x >> 6;
    const int cl = lane & 15;
    const int quad = lane >> 4;
    const int rowBase = blockIdx.x * 64 + wv * 16;
    const int ar = min(rowBase + cl, N_NODES - 1);
    const int bLane = cl * 32 + quad * 8;

    f32x4 acc[8];
    #pragma unroll
    for (int t = 0; t < 8; ++t) acc[t] = (f32x4){0.f, 0.f, 0.f, 0.f};

    #pragma unroll
    for (int c = 0; c < 4; ++c) {
        short8 af = loadA<true>(x, ar * 128 + c * 32 + quad * 8);
        const unsigned short* Bc = Wp1 + c * 4096 + bLane;
        #pragma unroll
        for (int t = 0; t < 8; ++t) {
            short8 bf = *(const short8*)(Bc + t * 512);
            acc[t] = __builtin_amdgcn_mfma_f32_16x16x32_bf16(af, bf, acc[t], 0, 0, 0);
        }
    }
    const int row0 = rowBase + quad * 4;
    #pragma unroll
    for (int t = 0; t < 8; ++t) {
        float bc = bp1[t * 16 + cl];
        #pragma unroll
        for (int g = 0; g < 4; ++g) {
            int r = row0 + g;
            if (r < N_NODES)
                Y[r * 128 + t * 16 + cl] = f2bf(fmaxf(acc[t][g] + bc, 0.0f));
        }
    }
}

// ---------------------------------------------------------------------------
// fused: max-pool + dual-GEMM + l2norm + (next-layer y-GEMM | fp32 out).
// = R4 structure (best measured, 336us total) with the gather rebuilt:
// R4's per-batch branches never skip (P(all 16 nodes of a wave agree)~1e-4)
// -- they only fragment the basic block and limit loads in flight (~16/lane,
// MfmaUtil 2.4%, occ 22% = grid-limited 3 blocks/CU). R5's clamp fixed the
// fragmentation but its __launch_bounds__(256,4) VGPR cap (52) re-serialized
// the loads. Now: clamp straight-line, edges 0-15 unconditional, 16-31 under
// ONE per-lane myDeg>16 guard (halves wasted clamped loads; P(deg>16)=0.43),
// static-indexed v[4][4] staging (64 VGPR of loads in flight), NO cap --
// grid is the residency limit so VGPR up to ~160 is free.
// Clamped slots re-read edge 0's row: re-max is a no-op, loads hit L1.
// relu'd bf16 >= 0 -> packed int16 max on raw bits exact; deg=0 -> 0.
// ---------------------------------------------------------------------------
template <bool A0F32, bool LAST>
__global__ __launch_bounds__(256) void fused_kernel(
    const void* __restrict__ A0,
    const unsigned short* __restrict__ Yl,          // gather source y_l
    const int* __restrict__ deg,
    const unsigned short* __restrict__ csr16,
    const unsigned short* __restrict__ B0, const unsigned short* __restrict__ B1,
    const float* __restrict__ bias,
    unsigned short* __restrict__ outH, float* __restrict__ outF,
    const unsigned short* __restrict__ Bnext, const float* __restrict__ bnext,
    unsigned short* __restrict__ Yout)
{
    constexpr int NT = LAST ? 4 : 8;
    constexpr int N = NT * 16;
    __shared__ unsigned short lds[4][16 * LROW];   // 17.4 KB, wave-private rows

    const int lane = threadIdx.x & 63;
    const int wv = threadIdx.x >> 6;
    const int cl = lane & 15;
    const int quad = lane >> 4;
    const int nodeBase = blockIdx.x * 64 + wv * 16;
    unsigned short* plw = &lds[wv][0];

    // ---- pool phase: 16 nodes/wave, 4 lanes/node, 32 dims/lane ----
    {
        const int n16 = lane >> 2;          // node within wave [0,16)
        const int g   = lane & 3;           // 64B dim slice [0,4)
        const int node = nodeBase + n16;
        const int nodeC = min(node, N_NODES - 1);
        const int myDeg = (node < N_NODES) ? min(deg[node], CAP) : 0;
        const unsigned short* csrn = csr16 + (nodeC << 6);
        const unsigned short* yg = Yl + g * 32;

        short8 p0 = (short8){0,0,0,0,0,0,0,0};
        short8 p1 = p0, p2 = p0, p3 = p0;

        if (myDeg > 0) {
            unsigned int idxw[16];
            *(uint4*)(idxw +  0) = *(const uint4*)(csrn +  0);
            *(uint4*)(idxw +  4) = *(const uint4*)(csrn +  8);
            *(uint4*)(idxw +  8) = *(const uint4*)(csrn + 16);
            *(uint4*)(idxw + 12) = *(const uint4*)(csrn + 24);
            const int s0 = (int)(idxw[0] & 0xFFFFu);   // edge 0 always valid

            // edges 0-15: straight-line, clamp-masked (waste ~10% at deg~16)
            #pragma unroll
            for (int b = 0; b < 4; ++b) {
                short8 v[4][4];
                #pragma unroll
                for (int u = 0; u < 4; ++u) {
                    const int jj = b * 4 + u;
                    int sj = (jj & 1) ? (int)(idxw[jj >> 1] >> 16)
                                      : (int)(idxw[jj >> 1] & 0xFFFFu);
                    sj = (jj < myDeg) ? sj : s0;       // cndmask, no branch
                    const short8* r = (const short8*)(yg + (sj << 7));
                    v[u][0] = r[0]; v[u][1] = r[1]; v[u][2] = r[2]; v[u][3] = r[3];
                }
                #pragma unroll
                for (int u = 0; u < 4; ++u) {
                    p0 = __builtin_elementwise_max(p0, v[u][0]);
                    p1 = __builtin_elementwise_max(p1, v[u][1]);
                    p2 = __builtin_elementwise_max(p2, v[u][2]);
                    p3 = __builtin_elementwise_max(p3, v[u][3]);
                }
            }
            // edges 16-31: one guard (lanes with deg<=16 masked off entirely)
            if (myDeg > 16) {
                #pragma unroll
                for (int b = 4; b < 8; ++b) {
                    short8 v[4][4];
                    #pragma unroll
                    for (int u = 0; u < 4; ++u) {
                        const int jj = b * 4 + u;
                        int sj = (jj & 1) ? (int)(idxw[jj >> 1] >> 16)
                                          : (int)(idxw[jj >> 1] & 0xFFFFu);
                        sj = (jj < myDeg) ? sj : s0;
                        const short8* r = (const short8*)(yg + (sj << 7));
                        v[u][0] = r[0]; v[u][1] = r[1]; v[u][2] = r[2]; v[u][3] = r[3];
                    }
                    #pragma unroll
                    for (int u = 0; u < 4; ++u) {
                        p0 = __builtin_elementwise_max(p0, v[u][0]);
                        p1 = __builtin_elementwise_max(p1, v[u][1]);
                        p2 = __builtin_elementwise_max(p2, v[u][2]);
                        p3 = __builtin_elementwise_max(p3, v[u][3]);
                    }
                }
            }
            for (int k = 32; k < myDeg; ++k) {         // rare tail (P~1e-4)
                const short8* r = (const short8*)(yg + ((int)csrn[k] << 7));
                p0 = __builtin_elementwise_max(p0, r[0]);
                p1 = __builtin_elementwise_max(p1, r[1]);
                p2 = __builtin_elementwise_max(p2, r[2]);
                p3 = __builtin_elementwise_max(p3, r[3]);
            }
        }
        unsigned short* pw = plw + n16 * LROW + g * 32;
        *(short8*)(pw)      = p0;
        *(short8*)(pw + 8)  = p1;
        *(short8*)(pw + 16) = p2;
        *(short8*)(pw + 24) = p3;
        // no barrier: this wave wrote rows it alone will read (DS in-order)
    }

    const int ar = min(nodeBase + cl, N_NODES - 1);
    const int aBase = ar * 128 + quad * 8;
    const int fBase = cl * LROW + quad * 8;     // LDS A-fragment base
    const int bLane = cl * 32 + quad * 8;

    f32x4 acc[NT];
    #pragma unroll
    for (int t = 0; t < NT; ++t) acc[t] = (f32x4){0.f, 0.f, 0.f, 0.f};

    #pragma unroll
    for (int c = 0; c < 4; ++c) {
        short8 a0 = loadA<A0F32>(A0, aBase + c * 32);
        short8 a1 = *(const short8*)(plw + fBase + c * 32);
        const unsigned short* B0c = B0 + c * (N * 32) + bLane;
        const unsigned short* B1c = B1 + c * (N * 32) + bLane;
        #pragma unroll
        for (int t = 0; t < NT; ++t) {
            short8 bf = *(const short8*)(B0c + t * 512);
            acc[t] = __builtin_amdgcn_mfma_f32_16x16x32_bf16(a0, bf, acc[t], 0, 0, 0);
        }
        #pragma unroll
        for (int t = 0; t < NT; ++t) {
            short8 bf = *(const short8*)(B1c + t * 512);
            acc[t] = __builtin_amdgcn_mfma_f32_16x16x32_bf16(a1, bf, acc[t], 0, 0, 0);
        }
    }

    #pragma unroll
    for (int t = 0; t < NT; ++t) {
        float bc = bias[t * 16 + cl];
        #pragma unroll
        for (int g = 0; g < 4; ++g) acc[t][g] += bc;
    }

    // ---- fused row-wise L2 norm (row lives in 16 lanes of this quad group) ----
    float inv[4];
    #pragma unroll
    for (int g = 0; g < 4; ++g) {
        float s = 0.f;
        #pragma unroll
        for (int t = 0; t < NT; ++t) s += acc[t][g] * acc[t][g];
        s += __shfl_xor(s, 1, 64);
        s += __shfl_xor(s, 2, 64);
        s += __shfl_xor(s, 4, 64);
        s += __shfl_xor(s, 8, 64);
        inv[g] = 1.0f / fmaxf(sqrtf(s), 1e-12f);
    }

    const int row0 = nodeBase + quad * 4;

    if (LAST) {
        #pragma unroll
        for (int t = 0; t < NT; ++t)
            #pragma unroll
            for (int g = 0; g < 4; ++g) {
                int r = row0 + g;
                if (r < N_NODES)
                    outF[r * N + t * 16 + cl] = fmaxf(acc[t][g] * inv[g], 0.0f);
            }
        return;
    }

    // h -> global (next fused's A0) + LDS stage (C-layout -> A-layout).
    // Overwrites the pool staging rows -- safe: all a1 reads precede these
    // writes in program order (same wave, DS in-order).
    #pragma unroll
    for (int t = 0; t < NT; ++t)
        #pragma unroll
        for (int g = 0; g < 4; ++g) {
            int r = row0 + g;
            unsigned short h = f2bf(fmaxf(acc[t][g] * inv[g], 0.0f));
            if (r < N_NODES) outH[r * 128 + t * 16 + cl] = h;
            plw[(quad * 4 + g) * LROW + t * 16 + cl] = h;
        }

    // ---- y-GEMM for the next layer: Yout = relu(h @ Bnext + bnext) ----
    f32x4 ya[8];
    #pragma unroll
    for (int t = 0; t < 8; ++t) ya[t] = (f32x4){0.f, 0.f, 0.f, 0.f};
    #pragma unroll
    for (int c = 0; c < 4; ++c) {
        short8 af = *(const short8*)(plw + cl * LROW + c * 32 + quad * 8);
        const unsigned short* Bc = Bnext + c * 4096 + bLane;
        #pragma unroll
        for (int t = 0; t < 8; ++t) {
            short8 bf = *(const short8*)(Bc + t * 512);
            ya[t] = __builtin_amdgcn_mfma_f32_16x16x32_bf16(af, bf, ya[t], 0, 0, 0);
        }
    }
    #pragma unroll
    for (int t = 0; t < 8; ++t) {
        float bc = bnext[t * 16 + cl];
        #pragma unroll
        for (int g = 0; g < 4; ++g) {
            int r = row0 + g;
            if (r < N_NODES)
                Yout[r * 128 + t * 16 + cl] = f2bf(fmaxf(ya[t][g] + bc, 0.0f));
        }
    }
}

extern "C" void kernel_launch(void* const* d_in, const int* in_sizes, int n_in,
                              void* d_out, int out_size, void* d_ws, size_t ws_size,
                              hipStream_t stream) {
    const float* x    = (const float*)d_in[0];
    const int*   esrc = (const int*)d_in[1];
    const int*   edst = (const int*)d_in[2];
    const float* Wp[3], *bp[3], *Ws[3], *Wn[3], *bb[3];
    for (int l = 0; l < 3; ++l) {
        Wp[l] = (const float*)d_in[3 + 5 * l];
        bp[l] = (const float*)d_in[4 + 5 * l];
        Ws[l] = (const float*)d_in[5 + 5 * l];
        Wn[l] = (const float*)d_in[6 + 5 * l];
        bb[l] = (const float*)d_in[7 + 5 * l];
    }

    const int NF = N_NODES * 128;
    unsigned short* YA  = (unsigned short*)d_ws;     // y ping
    unsigned short* YB  = YA + NF;                   // y pong
    unsigned short* PL  = YB + NF;                   // (unused; kept for layout)
    unsigned short* H1  = PL + NF;                   // h1
    unsigned short* H2  = H1 + NF;                   // h2
    unsigned short* Wpk = H2 + NF;                   // 9 * 16384 packed weights
    int* deg = (int*)(Wpk + 9 * 16384);              // 50000
    unsigned short* csr16 = (unsigned short*)(deg + N_NODES); // 50000*64

    auto WH = [&](int i) { return Wpk + i * 16384; };
    // order: 0=Wp1 1=Ws1 2=Wn1 3=Wp2 4=Ws2 5=Wn2 6=Wp3 7=Ws3 8=Wn3

    WDescs wd;
    wd.W[0] = Wp[0]; wd.N[0] = 128;
    wd.W[1] = Ws[0]; wd.N[1] = 128;
    wd.W[2] = Wn[0]; wd.N[2] = 128;
    wd.W[3] = Wp[1]; wd.N[3] = 128;
    wd.W[4] = Ws[1]; wd.N[4] = 128;
    wd.W[5] = Wn[1]; wd.N[5] = 128;
    wd.W[6] = Wp[2]; wd.N[6] = 128;
    wd.W[7] = Ws[2]; wd.N[7] = 64;
    wd.W[8] = Wn[2]; wd.N[8] = 64;

    // 1) prep: pack weights + zero deg
    prep_kernel<<<576, 256, 0, stream>>>(wd, Wpk, deg);
    // 2) Y1 = relu(x@Wp1+bp1) + one-shot CSR fill (R1 best-measured form)
    mix_kernel<<<GEMMB + CSRB, 256, 0, stream>>>(esrc, edst, deg, csr16,
                                                 x, WH(0), bp[0], YA);
    // 3) layer 1 (pool fused): gathers YA, A0 = x (fp32)
    fused_kernel<true, false><<<GEMMB, 256, 0, stream>>>(
        x, YA, deg, csr16, WH(1), WH(2), bb[0], H1, nullptr, WH(3), bp[1], YB);
    // 4) layer 2: gathers YB, A0 = H1
    fused_kernel<false, false><<<GEMMB, 256, 0, stream>>>(
        H1, YB, deg, csr16, WH(4), WH(5), bb[1], H2, nullptr, WH(6), bp[2], YA);
    // 5) layer 3: gathers YA, A0 = H2, fp32 out
    fused_kernel<false, true><<<GEMMB, 256, 0, stream>>>(
        H2, YA, deg, csr16, WH(7), WH(8), bb[2], nullptr, (float*)d_out,
        nullptr, nullptr, nullptr);
}

// Round 9
// 331.411 us; speedup vs baseline: 1.0953x; 1.0199x over previous
//
#include <hip/hip_runtime.h>
#include <math.h>

#define N_NODES 50000
#define N_EDGES 800000
#define CAP 64                 // fixed CSR capacity/node (deg~Poisson(16))
#define RANGES 8
#define NODES_PER_RANGE 6250   // 50000 / 8
#define GEMMB 782              // ceil(50000/64)
#define CHUNKS (N_EDGES / 256) // 3125 edge chunks of 256
#define CPB 8                  // chunks per CSR block (latency batching)
#define BPR ((CHUNKS + CPB - 1) / CPB)   // 391 blocks per range
#define CSRB (BPR * RANGES)    // 3128 csr blocks
#define LROW 136               // LDS row stride in shorts (272 B)

typedef __attribute__((ext_vector_type(8))) short short8;   // 8 bf16
typedef __attribute__((ext_vector_type(4))) float f32x4;    // 4 fp32 acc

// ---------------- bf16 helpers (RNE) ----------------
__device__ __forceinline__ unsigned short f2bf(float f) {
    unsigned int u = __float_as_uint(f);
    return (unsigned short)((u + 0x7FFFu + ((u >> 16) & 1u)) >> 16);
}

// A fragment load: row-major fp32 (inline convert) or bf16.
template <bool F32>
__device__ __forceinline__ short8 loadA(const void* A, int off) {
    short8 r;
    if (F32) {
        const float* p = (const float*)A + off;   // 32B aligned
        float4 f0 = *(const float4*)p;
        float4 f1 = *(const float4*)(p + 4);
        r[0] = (short)f2bf(f0.x); r[1] = (short)f2bf(f0.y);
        r[2] = (short)f2bf(f0.z); r[3] = (short)f2bf(f0.w);
        r[4] = (short)f2bf(f1.x); r[5] = (short)f2bf(f1.y);
        r[6] = (short)f2bf(f1.z); r[7] = (short)f2bf(f1.w);
    } else {
        r = *(const short8*)((const unsigned short*)A + off);
    }
    return r;
}

// ---------------------------------------------------------------------------
// Forced-depth gather primitives (R9): hipcc collapsed every source-level
// gather variant to ~68 VGPR / shallow pipelines (R4/R5/R8 all ~74us).
// These asm blocks pin 8 global_load_dwordx4 per batch into dedicated
// registers; the s_waitcnt asm takes the batch registers as "+v" operands
// so consumption cannot be hoisted above the wait (rule-#18-safe).
// Double-buffered A/B sets -> 16 loads/lane in flight in steady state.
// ---------------------------------------------------------------------------
__device__ __forceinline__ void issue8(short8 (&v)[8],
    const unsigned short* a0, const unsigned short* a1) {
    asm volatile(
        "global_load_dwordx4 %0, %8, off\n\t"
        "global_load_dwordx4 %1, %8, off offset:16\n\t"
        "global_load_dwordx4 %2, %8, off offset:32\n\t"
        "global_load_dwordx4 %3, %8, off offset:48\n\t"
        "global_load_dwordx4 %4, %9, off\n\t"
        "global_load_dwordx4 %5, %9, off offset:16\n\t"
        "global_load_dwordx4 %6, %9, off offset:32\n\t"
        "global_load_dwordx4 %7, %9, off offset:48"
        : "=&v"(v[0]), "=&v"(v[1]), "=&v"(v[2]), "=&v"(v[3]),
          "=&v"(v[4]), "=&v"(v[5]), "=&v"(v[6]), "=&v"(v[7])
        : "v"(a0), "v"(a1));
}

__device__ __forceinline__ void wait_vm8(short8 (&v)[8]) {
    asm volatile("s_waitcnt vmcnt(8)"
        : "+v"(v[0]), "+v"(v[1]), "+v"(v[2]), "+v"(v[3]),
          "+v"(v[4]), "+v"(v[5]), "+v"(v[6]), "+v"(v[7]) :: "memory");
}

__device__ __forceinline__ void wait_vm0(short8 (&v)[8]) {
    asm volatile("s_waitcnt vmcnt(0)"
        : "+v"(v[0]), "+v"(v[1]), "+v"(v[2]), "+v"(v[3]),
          "+v"(v[4]), "+v"(v[5]), "+v"(v[6]), "+v"(v[7]) :: "memory");
}

__device__ __forceinline__ void consume8(short8 (&p)[4], const short8 (&v)[8]) {
    p[0] = __builtin_elementwise_max(p[0], v[0]);
    p[1] = __builtin_elementwise_max(p[1], v[1]);
    p[2] = __builtin_elementwise_max(p[2], v[2]);
    p[3] = __builtin_elementwise_max(p[3], v[3]);
    p[0] = __builtin_elementwise_max(p[0], v[4]);
    p[1] = __builtin_elementwise_max(p[1], v[5]);
    p[2] = __builtin_elementwise_max(p[2], v[6]);
    p[3] = __builtin_elementwise_max(p[3], v[7]);
}

// ---------------------------------------------------------------------------
// prep: pack 9 weight matrices fp32 -> bf16 fragment layout; zero deg.
// Bp[((c*N + n)*4 + q)*8 + j] = W[(c*32 + q*8 + j)*N + n].
// ---------------------------------------------------------------------------
struct WDescs { const float* W[9]; int N[9]; };

__global__ __launch_bounds__(256) void prep_kernel(
    WDescs wd, unsigned short* __restrict__ Wpk, int* __restrict__ deg)
{
    const int nthr = gridDim.x * 256;
    const int tid = blockIdx.x * 256 + threadIdx.x;
    for (int id = tid; id < 9 * 16384; id += nthr) {
        int mi = id >> 14;
        int loc = id & 16383;
        int N = wd.N[mi];
        if (loc < 128 * N) {
            int c = loc / (N * 32);
            int n = (loc - c * N * 32) >> 5;
            int k = c * 32 + (loc & 31);
            Wpk[mi * 16384 + loc] = f2bf(wd.W[mi][k * N + n]);
        }
    }
    for (int i = tid; i < N_NODES; i += nthr) deg[i] = 0;
}

// ---------------------------------------------------------------------------
// mix (R1 best-measured form, ~50us): blocks [0,GEMMB) compute
// Y1 = relu(x@Wp1+bp1); blocks [GEMMB,+CSRB) build CSR one-shot
// (XCD-range-partitioned, CPB=8 index-load batching).
// R1-R3 lesson: issue-side restructuring moved mix 50<->59us; the cost is
// the scattered-atomic/scatter-store machinery itself. Keep as-is.
// ---------------------------------------------------------------------------
__global__ __launch_bounds__(256) void mix_kernel(
    const int* __restrict__ esrc, const int* __restrict__ edst,
    int* __restrict__ deg, unsigned short* __restrict__ csr16,
    const float* __restrict__ x, const unsigned short* __restrict__ Wp1,
    const float* __restrict__ bp1, unsigned short* __restrict__ Y)
{
    if (blockIdx.x >= GEMMB) {
        const int b = blockIdx.x - GEMMB;
        const int range = b & (RANGES - 1);
        const int cbase = (b >> 3) * CPB;
        const int lo = range * NODES_PER_RANGE;
        int d[CPB], s[CPB];
        #pragma unroll
        for (int i = 0; i < CPB; ++i) {
            const int c = cbase + i;
            const int e = c * 256 + threadIdx.x;
            const bool ok = (c < CHUNKS);
            d[i] = ok ? edst[e] : -1;        // coalesced, 16 loads in flight
            s[i] = ok ? esrc[e] : 0;
        }
        #pragma unroll
        for (int i = 0; i < CPB; ++i) {
            if ((unsigned)(d[i] - lo) < (unsigned)NODES_PER_RANGE) {
                int r = atomicAdd(&deg[d[i]], 1);
                if (r < CAP) csr16[(d[i] << 6) + r] = (unsigned short)s[i];
            }
        }
        return;
    }
    const int lane = threadIdx.x & 63;
    const int wv = threadIdx.x >> 6;
    const int cl = lane & 15;
    const int quad = lane >> 4;
    const int rowBase = blockIdx.x * 64 + wv * 16;
    const int ar = min(rowBase + cl, N_NODES - 1);
    const int bLane = cl * 32 + quad * 8;

    f32x4 acc[8];
    #pragma unroll
    for (int t = 0; t < 8; ++t) acc[t] = (f32x4){0.f, 0.f, 0.f, 0.f};

    #pragma unroll
    for (int c = 0; c < 4; ++c) {
        short8 af = loadA<true>(x, ar * 128 + c * 32 + quad * 8);
        const unsigned short* Bc = Wp1 + c * 4096 + bLane;
        #pragma unroll
        for (int t = 0; t < 8; ++t) {
            short8 bf = *(const short8*)(Bc + t * 512);
            acc[t] = __builtin_amdgcn_mfma_f32_16x16x32_bf16(af, bf, acc[t], 0, 0, 0);
        }
    }
    const int row0 = rowBase + quad * 4;
    #pragma unroll
    for (int t = 0; t < 8; ++t) {
        float bc = bp1[t * 16 + cl];
        #pragma unroll
        for (int g = 0; g < 4; ++g) {
            int r = row0 + g;
            if (r < N_NODES)
                Y[r * 128 + t * 16 + cl] = f2bf(fmaxf(acc[t][g] + bc, 0.0f));
        }
    }
}

// ---------------------------------------------------------------------------
// fused: max-pool + dual-GEMM + l2norm + (next-layer y-GEMM | fp32 out).
// R9: gather rewritten with asm-pinned pipelined loads (see issue8/wait_vm8
// above). Structure: 2-edge batches, A/B double-buffer, steady state 16
// loads/lane in flight; edges 16-31 run under the per-lane deg>16 exec mask
// INSIDE the same pipeline (both paths leave the same two sets outstanding
// -> uniform drain). Clamped slots re-read edge 0 (re-max no-op, L1 hit).
// relu'd bf16 >= 0 -> packed int16 max on raw bits exact; deg=0 -> 0.
// ---------------------------------------------------------------------------
template <bool A0F32, bool LAST>
__global__ __launch_bounds__(256) void fused_kernel(
    const void* __restrict__ A0,
    const unsigned short* __restrict__ Yl,          // gather source y_l
    const int* __restrict__ deg,
    const unsigned short* __restrict__ csr16,
    const unsigned short* __restrict__ B0, const unsigned short* __restrict__ B1,
    const float* __restrict__ bias,
    unsigned short* __restrict__ outH, float* __restrict__ outF,
    const unsigned short* __restrict__ Bnext, const float* __restrict__ bnext,
    unsigned short* __restrict__ Yout)
{
    constexpr int NT = LAST ? 4 : 8;
    constexpr int N = NT * 16;
    __shared__ unsigned short lds[4][16 * LROW];   // 17.4 KB, wave-private rows

    const int lane = threadIdx.x & 63;
    const int wv = threadIdx.x >> 6;
    const int cl = lane & 15;
    const int quad = lane >> 4;
    const int nodeBase = blockIdx.x * 64 + wv * 16;
    unsigned short* plw = &lds[wv][0];

    // ---- pool phase: 16 nodes/wave, 4 lanes/node, 32 dims/lane ----
    {
        const int n16 = lane >> 2;          // node within wave [0,16)
        const int g   = lane & 3;           // 64B dim slice [0,4)
        const int node = nodeBase + n16;
        const int nodeC = min(node, N_NODES - 1);
        const int myDeg = (node < N_NODES) ? min(deg[node], CAP) : 0;
        const unsigned short* csrn = csr16 + (nodeC << 6);
        const unsigned short* yg = Yl + g * 32;

        short8 p[4];
        p[0] = (short8){0,0,0,0,0,0,0,0};
        p[1] = p[0]; p[2] = p[0]; p[3] = p[0];

        if (myDeg > 0) {
            unsigned int idxw[16];
            *(uint4*)(idxw +  0) = *(const uint4*)(csrn +  0);
            *(uint4*)(idxw +  4) = *(const uint4*)(csrn +  8);
            *(uint4*)(idxw +  8) = *(const uint4*)(csrn + 16);
            *(uint4*)(idxw + 12) = *(const uint4*)(csrn + 24);
            const int s0 = (int)(idxw[0] & 0xFFFFu);   // edge 0 always valid

            auto eaddr = [&](int jj) -> const unsigned short* {
                int sj = (jj & 1) ? (int)(idxw[jj >> 1] >> 16)
                                  : (int)(idxw[jj >> 1] & 0xFFFFu);
                sj = (jj < myDeg) ? sj : s0;            // cndmask clamp
                return yg + (sj << 7);
            };

            short8 va[8], vb[8];
            // edges 0-15: pipelined, 16 loads/lane in flight
            issue8(va, eaddr(0),  eaddr(1));
            issue8(vb, eaddr(2),  eaddr(3));
            wait_vm8(va); consume8(p, va); issue8(va, eaddr(4),  eaddr(5));
            wait_vm8(vb); consume8(p, vb); issue8(vb, eaddr(6),  eaddr(7));
            wait_vm8(va); consume8(p, va); issue8(va, eaddr(8),  eaddr(9));
            wait_vm8(vb); consume8(p, vb); issue8(vb, eaddr(10), eaddr(11));
            wait_vm8(va); consume8(p, va); issue8(va, eaddr(12), eaddr(13));
            wait_vm8(vb); consume8(p, vb); issue8(vb, eaddr(14), eaddr(15));
            // edges 16-31 under per-lane exec mask; same pipeline shape, so
            // both paths end with two sets outstanding (va=older, vb=newer)
            if (myDeg > 16) {
                wait_vm8(va); consume8(p, va); issue8(va, eaddr(16), eaddr(17));
                wait_vm8(vb); consume8(p, vb); issue8(vb, eaddr(18), eaddr(19));
                wait_vm8(va); consume8(p, va); issue8(va, eaddr(20), eaddr(21));
                wait_vm8(vb); consume8(p, vb); issue8(vb, eaddr(22), eaddr(23));
                wait_vm8(va); consume8(p, va); issue8(va, eaddr(24), eaddr(25));
                wait_vm8(vb); consume8(p, vb); issue8(vb, eaddr(26), eaddr(27));
                wait_vm8(va); consume8(p, va); issue8(va, eaddr(28), eaddr(29));
                wait_vm8(vb); consume8(p, vb); issue8(vb, eaddr(30), eaddr(31));
            }
            // uniform drain
            wait_vm8(va); consume8(p, va);
            wait_vm0(vb); consume8(p, vb);

            for (int k = 32; k < myDeg; ++k) {         // rare tail (P~1e-4)
                const short8* r = (const short8*)(yg + ((int)csrn[k] << 7));
                p[0] = __builtin_elementwise_max(p[0], r[0]);
                p[1] = __builtin_elementwise_max(p[1], r[1]);
                p[2] = __builtin_elementwise_max(p[2], r[2]);
                p[3] = __builtin_elementwise_max(p[3], r[3]);
            }
        }
        unsigned short* pw = plw + n16 * LROW + g * 32;
        *(short8*)(pw)      = p[0];
        *(short8*)(pw + 8)  = p[1];
        *(short8*)(pw + 16) = p[2];
        *(short8*)(pw + 24) = p[3];
        // no barrier: this wave wrote rows it alone will read (DS in-order)
    }

    const int ar = min(nodeBase + cl, N_NODES - 1);
    const int aBase = ar * 128 + quad * 8;
    const int fBase = cl * LROW + quad * 8;     // LDS A-fragment base
    const int bLane = cl * 32 + quad * 8;

    f32x4 acc[NT];
    #pragma unroll
    for (int t = 0; t < NT; ++t) acc[t] = (f32x4){0.f, 0.f, 0.f, 0.f};

    #pragma unroll
    for (int c = 0; c < 4; ++c) {
        short8 a0 = loadA<A0F32>(A0, aBase + c * 32);
        short8 a1 = *(const short8*)(plw + fBase + c * 32);
        const unsigned short* B0c = B0 + c * (N * 32) + bLane;
        const unsigned short* B1c = B1 + c * (N * 32) + bLane;
        #pragma unroll
        for (int t = 0; t < NT; ++t) {
            short8 bf = *(const short8*)(B0c + t * 512);
            acc[t] = __builtin_amdgcn_mfma_f32_16x16x32_bf16(a0, bf, acc[t], 0, 0, 0);
        }
        #pragma unroll
        for (int t = 0; t < NT; ++t) {
            short8 bf = *(const short8*)(B1c + t * 512);
            acc[t] = __builtin_amdgcn_mfma_f32_16x16x32_bf16(a1, bf, acc[t], 0, 0, 0);
        }
    }

    #pragma unroll
    for (int t = 0; t < NT; ++t) {
        float bc = bias[t * 16 + cl];
        #pragma unroll
        for (int g = 0; g < 4; ++g) acc[t][g] += bc;
    }

    // ---- fused row-wise L2 norm (row lives in 16 lanes of this quad group) ----
    float inv[4];
    #pragma unroll
    for (int g = 0; g < 4; ++g) {
        float s = 0.f;
        #pragma unroll
        for (int t = 0; t < NT; ++t) s += acc[t][g] * acc[t][g];
        s += __shfl_xor(s, 1, 64);
        s += __shfl_xor(s, 2, 64);
        s += __shfl_xor(s, 4, 64);
        s += __shfl_xor(s, 8, 64);
        inv[g] = 1.0f / fmaxf(sqrtf(s), 1e-12f);
    }

    const int row0 = nodeBase + quad * 4;

    if (LAST) {
        #pragma unroll
        for (int t = 0; t < NT; ++t)
            #pragma unroll
            for (int g = 0; g < 4; ++g) {
                int r = row0 + g;
                if (r < N_NODES)
                    outF[r * N + t * 16 + cl] = fmaxf(acc[t][g] * inv[g], 0.0f);
            }
        return;
    }

    // h -> global (next fused's A0) + LDS stage (C-layout -> A-layout).
    // Overwrites the pool staging rows -- safe: all a1 reads precede these
    // writes in program order (same wave, DS in-order).
    #pragma unroll
    for (int t = 0; t < NT; ++t)
        #pragma unroll
        for (int g = 0; g < 4; ++g) {
            int r = row0 + g;
            unsigned short h = f2bf(fmaxf(acc[t][g] * inv[g], 0.0f));
            if (r < N_NODES) outH[r * 128 + t * 16 + cl] = h;
            plw[(quad * 4 + g) * LROW + t * 16 + cl] = h;
        }

    // ---- y-GEMM for the next layer: Yout = relu(h @ Bnext + bnext) ----
    f32x4 ya[8];
    #pragma unroll
    for (int t = 0; t < 8; ++t) ya[t] = (f32x4){0.f, 0.f, 0.f, 0.f};
    #pragma unroll
    for (int c = 0; c < 4; ++c) {
        short8 af = *(const short8*)(plw + cl * LROW + c * 32 + quad * 8);
        const unsigned short* Bc = Bnext + c * 4096 + bLane;
        #pragma unroll
        for (int t = 0; t < 8; ++t) {
            short8 bf = *(const short8*)(Bc + t * 512);
            ya[t] = __builtin_amdgcn_mfma_f32_16x16x32_bf16(af, bf, ya[t], 0, 0, 0);
        }
    }
    #pragma unroll
    for (int t = 0; t < 8; ++t) {
        float bc = bnext[t * 16 + cl];
        #pragma unroll
        for (int g = 0; g < 4; ++g) {
            int r = row0 + g;
            if (r < N_NODES)
                Yout[r * 128 + t * 16 + cl] = f2bf(fmaxf(ya[t][g] + bc, 0.0f));
        }
    }
}

extern "C" void kernel_launch(void* const* d_in, const int* in_sizes, int n_in,
                              void* d_out, int out_size, void* d_ws, size_t ws_size,
                              hipStream_t stream) {
    const float* x    = (const float*)d_in[0];
    const int*   esrc = (const int*)d_in[1];
    const int*   edst = (const int*)d_in[2];
    const float* Wp[3], *bp[3], *Ws[3], *Wn[3], *bb[3];
    for (int l = 0; l < 3; ++l) {
        Wp[l] = (const float*)d_in[3 + 5 * l];
        bp[l] = (const float*)d_in[4 + 5 * l];
        Ws[l] = (const float*)d_in[5 + 5 * l];
        Wn[l] = (const float*)d_in[6 + 5 * l];
        bb[l] = (const float*)d_in[7 + 5 * l];
    }

    const int NF = N_NODES * 128;
    unsigned short* YA  = (unsigned short*)d_ws;     // y ping
    unsigned short* YB  = YA + NF;                   // y pong
    unsigned short* PL  = YB + NF;                   // (unused; kept for layout)
    unsigned short* H1  = PL + NF;                   // h1
    unsigned short* H2  = H1 + NF;                   // h2
    unsigned short* Wpk = H2 + NF;                   // 9 * 16384 packed weights
    int* deg = (int*)(Wpk + 9 * 16384);              // 50000
    unsigned short* csr16 = (unsigned short*)(deg + N_NODES); // 50000*64

    auto WH = [&](int i) { return Wpk + i * 16384; };
    // order: 0=Wp1 1=Ws1 2=Wn1 3=Wp2 4=Ws2 5=Wn2 6=Wp3 7=Ws3 8=Wn3

    WDescs wd;
    wd.W[0] = Wp[0]; wd.N[0] = 128;
    wd.W[1] = Ws[0]; wd.N[1] = 128;
    wd.W[2] = Wn[0]; wd.N[2] = 128;
    wd.W[3] = Wp[1]; wd.N[3] = 128;
    wd.W[4] = Ws[1]; wd.N[4] = 128;
    wd.W[5] = Wn[1]; wd.N[5] = 128;
    wd.W[6] = Wp[2]; wd.N[6] = 128;
    wd.W[7] = Ws[2]; wd.N[7] = 64;
    wd.W[8] = Wn[2]; wd.N[8] = 64;

    // 1) prep: pack weights + zero deg
    prep_kernel<<<576, 256, 0, stream>>>(wd, Wpk, deg);
    // 2) Y1 = relu(x@Wp1+bp1) + one-shot CSR fill (R1 best-measured form)
    mix_kernel<<<GEMMB + CSRB, 256, 0, stream>>>(esrc, edst, deg, csr16,
                                                 x, WH(0), bp[0], YA);
    // 3) layer 1 (pool fused): gathers YA, A0 = x (fp32)
    fused_kernel<true, false><<<GEMMB, 256, 0, stream>>>(
        x, YA, deg, csr16, WH(1), WH(2), bb[0], H1, nullptr, WH(3), bp[1], YB);
    // 4) layer 2: gathers YB, A0 = H1
    fused_kernel<false, false><<<GEMMB, 256, 0, stream>>>(
        H1, YB, deg, csr16, WH(4), WH(5), bb[1], H2, nullptr, WH(6), bp[2], YA);
    // 5) layer 3: gathers YA, A0 = H2, fp32 out
    fused_kernel<false, true><<<GEMMB, 256, 0, stream>>>(
        H2, YA, deg, csr16, WH(7), WH(8), bb[2], nullptr, (float*)d_out,
        nullptr, nullptr, nullptr);
}